// Round 9
// baseline (74.493 us; speedup 1.0000x reference)
//
#include <hip/hip_runtime.h>

typedef short s16x8 __attribute__((ext_vector_type(8)));
typedef float f32x4 __attribute__((ext_vector_type(4)));

constexpr int F  = 24;
constexpr int NP = 276;   // F*(F-1)/2
constexpr int E  = 64;

__device__ __forceinline__ unsigned short f2bf(float f) {
    unsigned int u = __builtin_bit_cast(unsigned int, f);
    return (unsigned short)((u + 0x7FFFu + ((u >> 16) & 1u)) >> 16);  // RNE
}

__global__ __launch_bounds__(256)
void bilinear_kernel(const float* __restrict__ x, const float* __restrict__ W,
                     float* __restrict__ out)
{
    __shared__ unsigned int BtU[2][2048];   // 16 KB: W[p0],W[p0+1] bf16, swizzled

    // ---- XCD swizzle: 2208 = 8 XCD x 276; per XCD 2 batch-windows x 138 chunks
    const int bid = blockIdx.x;
    const int xcd = bid & 7;
    const int idx = bid >> 3;               // 0..275
    const int wl  = (idx >= 138) ? 1 : 0;
    const int ck  = idx - wl * 138;         // 0..137
    const int b0  = (xcd * 2 + wl) * 256;
    const int p0  = ck * 2;

    const int tid  = threadIdx.x;
    const int wv   = tid >> 6;
    const int ln   = tid & 63;
    const int lrow = ln & 15;
    const int lq   = ln >> 4;

    // decode pair p0 -> (i0,j0); p0+1 is its lexicographic successor
    int i0 = 0, rem = p0;
    while (rem >= F - 1 - i0) { rem -= F - 1 - i0; ++i0; }
    const int j0 = i0 + 1 + rem;
    int i1 = i0, j1 = j0 + 1;
    if (j1 == F) { i1 = i0 + 1; j1 = i1 + 1; }

    // ---- stage W[p0]^T and W[p0+1]^T into LDS as bf16, XOR-swizzled ----
    #pragma unroll
    for (int pr = 0; pr < 2; ++pr) {
        const float* Wp = W + (size_t)(p0 + pr) * E * E;
        #pragma unroll
        for (int it = 0; it < 8; ++it) {
            int q  = tid + it * 256;
            int f  = q & 63;
            int e2 = q >> 6;
            float w0 = Wp[(2 * e2) * E + f];
            float w1 = Wp[(2 * e2 + 1) * E + f];
            unsigned int pk = (unsigned int)f2bf(w0) | ((unsigned int)f2bf(w1) << 16);
            BtU[pr][f * 32 + (e2 ^ ((f & 7) << 2))] = pk;
        }
    }
    __syncthreads();

    // B fragments for both pairs, register-resident (statically indexed)
    s16x8 bfrag[2][4][2];
    #pragma unroll
    for (int pr = 0; pr < 2; ++pr) {
        const unsigned short* Bts = reinterpret_cast<const unsigned short*>(BtU[pr]);
        #pragma unroll
        for (int n = 0; n < 4; ++n) {
            int fc = n * 16 + lrow;
            #pragma unroll
            for (int kk = 0; kk < 2; ++kk) {
                int k0 = kk * 32 + lq * 8;
                int sidx = fc * 64 + (k0 ^ ((fc & 7) << 3));
                bfrag[pr][n][kk] = *reinterpret_cast<const s16x8*>(&Bts[sidx]);
            }
        }
    }

    #pragma unroll 1
    for (int s = 0; s < 4; ++s) {
        const int mbase = s * 64 + wv * 16;
        const int bA = b0 + mbase + lrow;

        // A fragments for pair 0 (row i0) and pair 1 (row i1)
        s16x8 af0[2], af1[2];
        #pragma unroll
        for (int kk = 0; kk < 2; ++kk) {
            int k0 = kk * 32 + lq * 8;
            const float4* ap0 = reinterpret_cast<const float4*>(
                x + ((size_t)bA * F + i0) * E + k0);
            float4 lo = ap0[0], hi = ap0[1];
            s16x8 a;
            a[0] = (short)f2bf(lo.x); a[1] = (short)f2bf(lo.y);
            a[2] = (short)f2bf(lo.z); a[3] = (short)f2bf(lo.w);
            a[4] = (short)f2bf(hi.x); a[5] = (short)f2bf(hi.y);
            a[6] = (short)f2bf(hi.z); a[7] = (short)f2bf(hi.w);
            af0[kk] = a;
            const float4* ap1 = reinterpret_cast<const float4*>(
                x + ((size_t)bA * F + i1) * E + k0);
            lo = ap1[0]; hi = ap1[1];
            a[0] = (short)f2bf(lo.x); a[1] = (short)f2bf(lo.y);
            a[2] = (short)f2bf(lo.z); a[3] = (short)f2bf(lo.w);
            a[4] = (short)f2bf(hi.x); a[5] = (short)f2bf(hi.y);
            a[6] = (short)f2bf(hi.z); a[7] = (short)f2bf(hi.w);
            af1[kk] = a;
        }

        f32x4 acc0[4], acc1[4];
        #pragma unroll
        for (int n = 0; n < 4; ++n) {
            acc0[n] = (f32x4){0.f, 0.f, 0.f, 0.f};
            acc0[n] = __builtin_amdgcn_mfma_f32_16x16x32_bf16(af0[0], bfrag[0][n][0], acc0[n], 0, 0, 0);
            acc0[n] = __builtin_amdgcn_mfma_f32_16x16x32_bf16(af0[1], bfrag[0][n][1], acc0[n], 0, 0, 0);
            acc1[n] = (f32x4){0.f, 0.f, 0.f, 0.f};
            acc1[n] = __builtin_amdgcn_mfma_f32_16x16x32_bf16(af1[0], bfrag[1][n][0], acc1[n], 0, 0, 0);
            acc1[n] = __builtin_amdgcn_mfma_f32_16x16x32_bf16(af1[1], bfrag[1][n][1], acc1[n], 0, 0, 0);
        }

        // epilogue: pair-adjacent nt stores -> 512 B contiguous DRAM chunks
        #pragma unroll
        for (int n = 0; n < 4; ++n) {
            int fc = n * 16 + lrow;
            #pragma unroll
            for (int r = 0; r < 4; ++r) {
                int b = b0 + mbase + lq * 4 + r;
                float xj0 = x[((size_t)b * F + j0) * E + fc];
                float xj1 = x[((size_t)b * F + j1) * E + fc];
                float* op = out + ((size_t)b * NP + p0) * E + fc;
                __builtin_nontemporal_store(acc0[n][r] * xj0, op);
                __builtin_nontemporal_store(acc1[n][r] * xj1, op + E);
            }
        }
    }
}

extern "C" void kernel_launch(void* const* d_in, const int* in_sizes, int n_in,
                              void* d_out, int out_size, void* d_ws, size_t ws_size,
                              hipStream_t stream)
{
    const float* x = (const float*)d_in[0];
    const float* W = (const float*)d_in[1];
    float* out = (float*)d_out;
    dim3 grid(138 * 16, 1, 1);   // 2208 = 8 XCDs x 276
    bilinear_kernel<<<grid, 256, 0, stream>>>(x, W, out);
}

// Round 10
// 71.206 us; speedup vs baseline: 1.0462x; 1.0462x over previous
//
#include <hip/hip_runtime.h>

typedef short s16x8 __attribute__((ext_vector_type(8)));
typedef float f32x4 __attribute__((ext_vector_type(4)));

constexpr int F  = 24;
constexpr int NP = 276;   // F*(F-1)/2
constexpr int E  = 64;
constexpr int TS = 68;    // LDS transpose stripe row stride (floats): 68 % 32 == 4
                          // -> scatter banks 2-way (free), gather balanced

__device__ __forceinline__ unsigned short f2bf(float f) {
    unsigned int u = __builtin_bit_cast(unsigned int, f);
    return (unsigned short)((u + 0x7FFFu + ((u >> 16) & 1u)) >> 16);  // RNE
}

__global__ __launch_bounds__(256)
void bilinear_kernel(const float* __restrict__ x, const float* __restrict__ W,
                     float* __restrict__ out)
{
    __shared__ unsigned int BtU[2048];     // 8 KB: W[p]^T bf16, XOR-swizzled
    __shared__ float Tbuf[4][16 * TS];     // 17.4 KB: per-wave transpose stripes

    // ---- XCD-aware swizzle (T1, as R4/R8) ----
    const int bid = blockIdx.x;
    const int xcd = bid & 7;
    const int idx = bid >> 3;              // 0..551
    const int wl  = (idx >= NP) ? 1 : 0;
    const int p   = idx - wl * NP;
    const int b0  = (xcd * 2 + wl) * 256;

    const int tid  = threadIdx.x;
    const int wv   = tid >> 6;
    const int ln   = tid & 63;
    const int lrow = ln & 15;
    const int lq   = ln >> 4;

    // decode pair (i, j)
    int i = 0, rem = p;
    while (rem >= F - 1 - i) { rem -= F - 1 - i; ++i; }
    const int j = i + 1 + rem;

    // ---- stage W[p]^T into LDS as bf16, XOR-swizzled (R4 verbatim) ----
    const float* Wp = W + (size_t)p * E * E;
    #pragma unroll
    for (int it = 0; it < 8; ++it) {
        int q  = tid + it * 256;
        int f  = q & 63;
        int e2 = q >> 6;
        float w0 = Wp[(2 * e2) * E + f];
        float w1 = Wp[(2 * e2 + 1) * E + f];
        unsigned int pk = (unsigned int)f2bf(w0) | ((unsigned int)f2bf(w1) << 16);
        BtU[f * 32 + (e2 ^ ((f & 7) << 2))] = pk;
    }
    __syncthreads();

    const unsigned short* Bts = reinterpret_cast<const unsigned short*>(BtU);

    // B fragments (W^T), register-resident
    s16x8 bfrag[4][2];
    #pragma unroll
    for (int n = 0; n < 4; ++n) {
        int fc = n * 16 + lrow;
        #pragma unroll
        for (int kk = 0; kk < 2; ++kk) {
            int k0 = kk * 32 + lq * 8;
            int sidx = fc * 64 + (k0 ^ ((fc & 7) << 3));
            bfrag[n][kk] = *reinterpret_cast<const s16x8*>(&Bts[sidx]);
        }
    }

    float* stripe = Tbuf[wv];   // this wave's private 16-row stripe

    #pragma unroll 1
    for (int s = 0; s < 4; ++s) {
        const int mbase = s * 64 + wv * 16;

        // A fragments straight from global (L2-hot after swizzle)
        s16x8 afrag[2];
        #pragma unroll
        for (int kk = 0; kk < 2; ++kk) {
            int b  = b0 + mbase + lrow;
            int k0 = kk * 32 + lq * 8;
            const float4* ap = reinterpret_cast<const float4*>(
                x + ((size_t)b * F + i) * E + k0);
            float4 lo = ap[0], hi = ap[1];
            s16x8 a;
            a[0] = (short)f2bf(lo.x); a[1] = (short)f2bf(lo.y);
            a[2] = (short)f2bf(lo.z); a[3] = (short)f2bf(lo.w);
            a[4] = (short)f2bf(hi.x); a[5] = (short)f2bf(hi.y);
            a[6] = (short)f2bf(hi.z); a[7] = (short)f2bf(hi.w);
            afrag[kk] = a;
        }

        f32x4 acc[4];
        #pragma unroll
        for (int n = 0; n < 4; ++n) {
            acc[n] = (f32x4){0.f, 0.f, 0.f, 0.f};
            acc[n] = __builtin_amdgcn_mfma_f32_16x16x32_bf16(afrag[0], bfrag[n][0], acc[n], 0, 0, 0);
            acc[n] = __builtin_amdgcn_mfma_f32_16x16x32_bf16(afrag[1], bfrag[n][1], acc[n], 0, 0, 0);
        }

        // ---- scatter acc into the wave-private LDS stripe ----
        // acc[n][r] = D[b_loc = lq*4 + r][f = n*16 + lrow]
        // write bank = (16*lq + 4*r + 16*n + lrow) % 32 -> 2-way max (free)
        #pragma unroll
        for (int n = 0; n < 4; ++n)
            #pragma unroll
            for (int r = 0; r < 4; ++r)
                stripe[(lq * 4 + r) * TS + n * 16 + lrow] = acc[n][r];
        // no barrier: producer and consumer are the same wave

        // ---- gather row-major, * xj (float4), NT dwordx4 store ----
        // per instruction: 4 segments x 256 B -> minimal TA transactions
        #pragma unroll
        for (int c = 0; c < 4; ++c) {
            const int rloc = c * 4 + lq;                 // 0..15
            const f32x4 v = *reinterpret_cast<const f32x4*>(
                &stripe[rloc * TS + lrow * 4]);
            const int b = b0 + mbase + rloc;
            const f32x4 xj = *reinterpret_cast<const f32x4*>(
                x + ((size_t)b * F + j) * E + lrow * 4);
            __builtin_nontemporal_store(v * xj, reinterpret_cast<f32x4*>(
                out + ((size_t)b * NP + p) * E + lrow * 4));
        }
    }
}

extern "C" void kernel_launch(void* const* d_in, const int* in_sizes, int n_in,
                              void* d_out, int out_size, void* d_ws, size_t ws_size,
                              hipStream_t stream)
{
    const float* x = (const float*)d_in[0];
    const float* W = (const float*)d_in[1];
    float* out = (float*)d_out;
    dim3 grid(NP * 16, 1, 1);   // 4416 = 8 XCDs x 552
    bilinear_kernel<<<grid, 256, 0, stream>>>(x, W, out);
}

// Round 11
// 67.213 us; speedup vs baseline: 1.1083x; 1.0594x over previous
//
#include <hip/hip_runtime.h>

typedef short s16x8 __attribute__((ext_vector_type(8)));
typedef float f32x4 __attribute__((ext_vector_type(4)));

constexpr int F  = 24;
constexpr int NP = 276;   // F*(F-1)/2
constexpr int E  = 64;
constexpr int TS = 68;    // LDS transpose stripe row stride (floats): 68 % 32 == 4

__device__ __forceinline__ unsigned short f2bf(float f) {
    unsigned int u = __builtin_bit_cast(unsigned int, f);
    return (unsigned short)((u + 0x7FFFu + ((u >> 16) & 1u)) >> 16);  // RNE
}

__global__ __launch_bounds__(256)
void bilinear_kernel(const float* __restrict__ x, const float* __restrict__ W,
                     float* __restrict__ out)
{
    __shared__ unsigned int BtU[2048];     // 8 KB: W[p]^T bf16, XOR-swizzled
    __shared__ float Tbuf[4][16 * TS];     // 17.4 KB: per-wave transpose stripes

    // ---- XCD swizzle: block = 1 pair x 512 batches (the XCD's full window)
    // grid 2208 = 8 XCD x 276 pairs; W staged ONCE per (XCD, pair).
    const int bid = blockIdx.x;
    const int xcd = bid & 7;
    const int p   = bid >> 3;              // 0..275
    const int b0  = xcd * 512;

    const int tid  = threadIdx.x;
    const int wv   = tid >> 6;
    const int ln   = tid & 63;
    const int lrow = ln & 15;
    const int lq   = ln >> 4;

    // decode pair (i, j)
    int i = 0, rem = p;
    while (rem >= F - 1 - i) { rem -= F - 1 - i; ++i; }
    const int j = i + 1 + rem;

    // ---- stage W[p]^T into LDS as bf16, XOR-swizzled (R10 verbatim) ----
    const float* Wp = W + (size_t)p * E * E;
    #pragma unroll
    for (int it = 0; it < 8; ++it) {
        int q  = tid + it * 256;
        int f  = q & 63;
        int e2 = q >> 6;
        float w0 = Wp[(2 * e2) * E + f];
        float w1 = Wp[(2 * e2 + 1) * E + f];
        unsigned int pk = (unsigned int)f2bf(w0) | ((unsigned int)f2bf(w1) << 16);
        BtU[f * 32 + (e2 ^ ((f & 7) << 2))] = pk;
    }
    __syncthreads();

    const unsigned short* Bts = reinterpret_cast<const unsigned short*>(BtU);

    // B fragments (W^T), register-resident
    s16x8 bfrag[4][2];
    #pragma unroll
    for (int n = 0; n < 4; ++n) {
        int fc = n * 16 + lrow;
        #pragma unroll
        for (int kk = 0; kk < 2; ++kk) {
            int k0 = kk * 32 + lq * 8;
            int sidx = fc * 64 + (k0 ^ ((fc & 7) << 3));
            bfrag[n][kk] = *reinterpret_cast<const s16x8*>(&Bts[sidx]);
        }
    }

    float* stripe = Tbuf[wv];   // this wave's private 16-row stripe

    #pragma unroll 1
    for (int s = 0; s < 8; ++s) {
        const int mbase = s * 64 + wv * 16;

        // A fragments straight from global (L2-hot after swizzle)
        s16x8 afrag[2];
        #pragma unroll
        for (int kk = 0; kk < 2; ++kk) {
            int b  = b0 + mbase + lrow;
            int k0 = kk * 32 + lq * 8;
            const float4* ap = reinterpret_cast<const float4*>(
                x + ((size_t)b * F + i) * E + k0);
            float4 lo = ap[0], hi = ap[1];
            s16x8 a;
            a[0] = (short)f2bf(lo.x); a[1] = (short)f2bf(lo.y);
            a[2] = (short)f2bf(lo.z); a[3] = (short)f2bf(lo.w);
            a[4] = (short)f2bf(hi.x); a[5] = (short)f2bf(hi.y);
            a[6] = (short)f2bf(hi.z); a[7] = (short)f2bf(hi.w);
            afrag[kk] = a;
        }

        f32x4 acc[4];
        #pragma unroll
        for (int n = 0; n < 4; ++n) {
            acc[n] = (f32x4){0.f, 0.f, 0.f, 0.f};
            acc[n] = __builtin_amdgcn_mfma_f32_16x16x32_bf16(afrag[0], bfrag[n][0], acc[n], 0, 0, 0);
            acc[n] = __builtin_amdgcn_mfma_f32_16x16x32_bf16(afrag[1], bfrag[n][1], acc[n], 0, 0, 0);
        }

        // ---- scatter acc into the wave-private LDS stripe (2-way banks) ----
        #pragma unroll
        for (int n = 0; n < 4; ++n)
            #pragma unroll
            for (int r = 0; r < 4; ++r)
                stripe[(lq * 4 + r) * TS + n * 16 + lrow] = acc[n][r];
        // no barrier: producer and consumer are the same wave

        // ---- gather row-major, * xj (float4), NT dwordx4 store ----
        #pragma unroll
        for (int c = 0; c < 4; ++c) {
            const int rloc = c * 4 + lq;                 // 0..15
            const f32x4 v = *reinterpret_cast<const f32x4*>(
                &stripe[rloc * TS + lrow * 4]);
            const int b = b0 + mbase + rloc;
            const f32x4 xj = *reinterpret_cast<const f32x4*>(
                x + ((size_t)b * F + j) * E + lrow * 4);
            __builtin_nontemporal_store(v * xj, reinterpret_cast<f32x4*>(
                out + ((size_t)b * NP + p) * E + lrow * 4));
        }
    }
}

extern "C" void kernel_launch(void* const* d_in, const int* in_sizes, int n_in,
                              void* d_out, int out_size, void* d_ws, size_t ws_size,
                              hipStream_t stream)
{
    const float* x = (const float*)d_in[0];
    const float* W = (const float*)d_in[1];
    float* out = (float*)d_out;
    dim3 grid(NP * 8, 1, 1);   // 2208 = 8 XCDs x 276 pairs
    bilinear_kernel<<<grid, 256, 0, stream>>>(x, W, out);
}